// Round 2
// baseline (657.619 us; speedup 1.0000x reference)
//
#include <hip/hip_runtime.h>
#include <stdint.h>

// Problem constants (fixed by the reference): N=7+1 blocks, B*L=8192, D=2048.
#define NB   8
#define DDIM 2048
#define BLK  256

__global__ __launch_bounds__(BLK) void attn_residual_kernel(
    const float* __restrict__ blocks,   // [7][BL][D] f32
    const float* __restrict__ partial,  // [BL][D] f32
    const float* __restrict__ scale,    // [D] f32
    const float* __restrict__ proj,     // [D] f32
    float*       __restrict__ out,      // [BL][D] f32
    int BL)
{
    const int bl = blockIdx.x;              // one workgroup per (b,l)
    const int t  = threadIdx.x;
    const size_t row     = (size_t)bl * DDIM;
    const size_t nstride = (size_t)BL * DDIM;
    const int dA = t * 4;                   // chunk A: [0, 1024)
    const int dB = t * 4 + 1024;            // chunk B: [1024, 2048)

    // p = proj * norm_scale for this thread's 8 d's
    const float4 prA = *(const float4*)(proj  + dA);
    const float4 prB = *(const float4*)(proj  + dB);
    const float4 scA = *(const float4*)(scale + dA);
    const float4 scB = *(const float4*)(scale + dB);
    const float4 pA = make_float4(prA.x*scA.x, prA.y*scA.y, prA.z*scA.z, prA.w*scA.w);
    const float4 pB = make_float4(prB.x*scB.x, prB.y*scB.y, prB.z*scB.z, prB.w*scB.w);

    // Load all 8 blocks' 8 elements into registers (single HBM pass).
    float4 vA[NB], vB[NB];
    #pragma unroll
    for (int n = 0; n < NB - 1; ++n) {
        const float* src = blocks + (size_t)n * nstride + row;
        vA[n] = *(const float4*)(src + dA);
        vB[n] = *(const float4*)(src + dB);
    }
    vA[NB-1] = *(const float4*)(partial + row + dA);
    vB[NB-1] = *(const float4*)(partial + row + dB);

    // Per-thread partial sum-of-squares and proj-dot per block n
    float ss[NB], dt[NB];
    #pragma unroll
    for (int n = 0; n < NB; ++n) {
        float s = 0.f, d = 0.f;
        s = fmaf(vA[n].x, vA[n].x, s); s = fmaf(vA[n].y, vA[n].y, s);
        s = fmaf(vA[n].z, vA[n].z, s); s = fmaf(vA[n].w, vA[n].w, s);
        s = fmaf(vB[n].x, vB[n].x, s); s = fmaf(vB[n].y, vB[n].y, s);
        s = fmaf(vB[n].z, vB[n].z, s); s = fmaf(vB[n].w, vB[n].w, s);
        d = fmaf(pA.x, vA[n].x, d); d = fmaf(pA.y, vA[n].y, d);
        d = fmaf(pA.z, vA[n].z, d); d = fmaf(pA.w, vA[n].w, d);
        d = fmaf(pB.x, vB[n].x, d); d = fmaf(pB.y, vB[n].y, d);
        d = fmaf(pB.z, vB[n].z, d); d = fmaf(pB.w, vB[n].w, d);
        ss[n] = s; dt[n] = d;
    }

    // Wave (64-lane) shuffle reduction of the 16 partials
    #pragma unroll
    for (int n = 0; n < NB; ++n) {
        float a = ss[n], b = dt[n];
        #pragma unroll
        for (int off = 32; off > 0; off >>= 1) {
            a += __shfl_down(a, off, 64);
            b += __shfl_down(b, off, 64);
        }
        ss[n] = a; dt[n] = b;
    }

    __shared__ float red[4][2][NB];
    const int wave = t >> 6, lane = t & 63;
    if (lane == 0) {
        #pragma unroll
        for (int n = 0; n < NB; ++n) {
            red[wave][0][n] = ss[n];
            red[wave][1][n] = dt[n];
        }
    }
    __syncthreads();

    // Every thread redundantly finishes the reduction + softmax (broadcast LDS reads)
    float w[NB];
    float m = -1e30f;
    #pragma unroll
    for (int n = 0; n < NB; ++n) {
        float s = red[0][0][n] + red[1][0][n] + red[2][0][n] + red[3][0][n];
        float d = red[0][1][n] + red[1][1][n] + red[2][1][n] + red[3][1][n];
        float rms = sqrtf(s * (1.0f / DDIM) + 1e-6f);
        float logit = d / rms;
        w[n] = logit;
        m = fmaxf(m, logit);
    }
    float denom = 0.f;
    #pragma unroll
    for (int n = 0; n < NB; ++n) {
        w[n] = __expf(w[n] - m);
        denom += w[n];
    }
    const float inv = 1.0f / denom;

    // Weighted sum over n, two coalesced float4 stores
    float4 oA = make_float4(0.f, 0.f, 0.f, 0.f);
    float4 oB = make_float4(0.f, 0.f, 0.f, 0.f);
    #pragma unroll
    for (int n = 0; n < NB; ++n) {
        const float wn = w[n];
        oA.x = fmaf(wn, vA[n].x, oA.x); oA.y = fmaf(wn, vA[n].y, oA.y);
        oA.z = fmaf(wn, vA[n].z, oA.z); oA.w = fmaf(wn, vA[n].w, oA.w);
        oB.x = fmaf(wn, vB[n].x, oB.x); oB.y = fmaf(wn, vB[n].y, oB.y);
        oB.z = fmaf(wn, vB[n].z, oB.z); oB.w = fmaf(wn, vB[n].w, oB.w);
    }
    oA.x *= inv; oA.y *= inv; oA.z *= inv; oA.w *= inv;
    oB.x *= inv; oB.y *= inv; oB.z *= inv; oB.w *= inv;
    *(float4*)(out + row + dA) = oA;
    *(float4*)(out + row + dB) = oB;
}

extern "C" void kernel_launch(void* const* d_in, const int* in_sizes, int n_in,
                              void* d_out, int out_size, void* d_ws, size_t ws_size,
                              hipStream_t stream) {
    const float* blocks  = (const float*)d_in[0];
    const float* partial = (const float*)d_in[1];
    const float* scale   = (const float*)d_in[2];
    const float* proj    = (const float*)d_in[3];
    float* out = (float*)d_out;

    const int BL = in_sizes[1] / DDIM;   // B*L = 8192
    attn_residual_kernel<<<dim3(BL), dim3(BLK), 0, stream>>>(
        blocks, partial, scale, proj, out, BL);
}